// Round 1
// baseline (2974.677 us; speedup 1.0000x reference)
//
#include <hip/hip_runtime.h>
#include <hip/hip_bf16.h>

#define HW 10000
#define NC 256

// ---------------- workspace layout (float offsets) ----------------
#define WS_OFF     0          // 50*HW   = 500000
#define WS_ALIGNED 500000     // 256*HW  = 2560000
#define WS_YBUF    3060000    // 256*HW  = 2560000
#define WS_ASUM    5620000    // 256*HW  = 2560000
#define WS_POOLED  8180000    // 256
#define WS_ATTN    8180256    // 256
#define WS_WGT     8180512    // 2*256
#define WS_INVW    8181024    // 256
#define WS_GMV     8181280    // 16 (8 mean, 8 rstd)

// ---------------- block-wide sum (256 threads) ----------------
__device__ __forceinline__ float block_sum(float v, volatile float* sh) {
#pragma unroll
  for (int o = 32; o > 0; o >>= 1) v += __shfl_down(v, o);
  __syncthreads();  // protect sh reuse across successive calls
  if ((threadIdx.x & 63) == 0) sh[threadIdx.x >> 6] = v;
  __syncthreads();
  return sh[0] + sh[1] + sh[2] + sh[3];
}

// ---------------- offset 1x1 conv: out[50,HW] = W[50,512] @ concat(cur,hist) + b ----------------
__global__ void offset_gemm(const float* __restrict__ cur, const float* __restrict__ hist,
                            const float* __restrict__ w, const float* __restrict__ b,
                            float* __restrict__ out) {
  const int p = blockIdx.x * 256 + threadIdx.x;
  const bool act = p < HW;
  float acc[50];
#pragma unroll
  for (int o = 0; o < 50; o++) acc[o] = b[o];
  for (int c0 = 0; c0 < 512; c0 += 8) {
    float v[8];
#pragma unroll
    for (int j = 0; j < 8; j++) {
      const int c = c0 + j;
      v[j] = act ? (c < NC ? cur[c * HW + p] : hist[(c - NC) * HW + p]) : 0.f;
    }
#pragma unroll
    for (int o = 0; o < 50; o++) {
#pragma unroll
      for (int j = 0; j < 8; j++) acc[o] += w[o * 512 + c0 + j] * v[j];
    }
  }
  if (act) {
#pragma unroll
    for (int o = 0; o < 50; o++) out[o * HW + p] = acc[o];
  }
}

// ---------------- deformable depthwise conv ----------------
// grid (ceil(HW/64), 8); block 256. Each thread: 1 position, 8 channels.
__global__ void deform_kernel(const float* __restrict__ hist, const float* __restrict__ off,
                              const float* __restrict__ dw, float* __restrict__ aligned) {
  const int lane = threadIdx.x & 63;
  const int sub = threadIdx.x >> 6;  // 0..3 (wave-uniform)
  const int p = blockIdx.x * 64 + lane;
  if (p >= HW) return;
  const int y = p / 100;
  const int x = p - y * 100;
  const int cbase = blockIdx.y * 32 + sub * 8;
  float acc[8];
#pragma unroll
  for (int k = 0; k < 8; k++) acc[k] = 0.f;

  for (int t = 0; t < 25; t++) {
    const float dy = off[(2 * t) * HW + p];
    const float dx = off[(2 * t + 1) * HW + p];
    const float ys = (float)(y + t / 5 - 2) + dy;
    const float xs = (float)(x + t % 5 - 2) + dx;
    const float y0f = floorf(ys), x0f = floorf(xs);
    const int y0 = (int)y0f, x0 = (int)x0f;
    const float wy = ys - y0f, wx = xs - x0f;
    const bool vy0 = (y0 >= 0) && (y0 <= 99);
    const bool vy1 = (y0 + 1 >= 0) && (y0 + 1 <= 99);
    const bool vx0 = (x0 >= 0) && (x0 <= 99);
    const bool vx1 = (x0 + 1 >= 0) && (x0 + 1 <= 99);
    const float w00 = (vy0 && vx0) ? (1.f - wy) * (1.f - wx) : 0.f;
    const float w01 = (vy0 && vx1) ? (1.f - wy) * wx : 0.f;
    const float w10 = (vy1 && vx0) ? wy * (1.f - wx) : 0.f;
    const float w11 = (vy1 && vx1) ? wy * wx : 0.f;
    const int yc0 = min(max(y0, 0), 99), yc1 = min(max(y0 + 1, 0), 99);
    const int xc0 = min(max(x0, 0), 99), xc1 = min(max(x0 + 1, 0), 99);
    const int i00 = yc0 * 100 + xc0, i01 = yc0 * 100 + xc1;
    const int i10 = yc1 * 100 + xc0, i11 = yc1 * 100 + xc1;
#pragma unroll
    for (int k = 0; k < 8; k++) {
      const float* hp = hist + (cbase + k) * HW;
      const float s = w00 * hp[i00] + w01 * hp[i01] + w10 * hp[i10] + w11 * hp[i11];
      acc[k] += dw[(cbase + k) * 25 + t] * s;
    }
  }
#pragma unroll
  for (int k = 0; k < 8; k++) aligned[(cbase + k) * HW + p] = acc[k];
}

// ---------------- per-channel reductions: pooled = mean(cur-aligned), wgt = sigmoid(-mean|cur-hist|) ----------------
__global__ void reduce_pw(const float* __restrict__ cur, const float* __restrict__ aligned,
                          const float* __restrict__ hist, float* __restrict__ pooled,
                          float* __restrict__ wgt) {
  __shared__ float sh[4];
  const int c = blockIdx.x;
  float s1 = 0.f, s2 = 0.f;
  for (int i = threadIdx.x; i < HW; i += 256) {
    const float cv = cur[c * HW + i];
    s1 += cv - aligned[c * HW + i];
    s2 += fabsf(cv - hist[c * HW + i]);
  }
  s1 = block_sum(s1, sh);
  s2 = block_sum(s2, sh);
  if (threadIdx.x == 0) {
    pooled[c] = s1 * (1.f / (float)HW);
    wgt[c] = 1.f / (1.f + expf(s2 * (1.f / (float)HW)));  // sigmoid(-diff)
  }
}

// ---------------- channel attention MLP ----------------
__global__ void attn_kernel(const float* __restrict__ pooled, const float* __restrict__ w1,
                            const float* __restrict__ w2, float* __restrict__ attn) {
  __shared__ float pl[256], hid[32];
  const int t = threadIdx.x;
  pl[t] = pooled[t];
  __syncthreads();
  if (t < 32) {
    float s = 0.f;
    for (int c = 0; c < 256; c++) s += w1[t * 256 + c] * pl[c];
    hid[t] = fmaxf(s, 0.f);
  }
  __syncthreads();
  float s = 0.f;
#pragma unroll
  for (int m = 0; m < 32; m++) s += w2[t * 32 + m] * hid[m];
  attn[t] = 1.f / (1.f + expf(-s));
}

// ---------------- 3x3 conv, 256->256, SAME pad. in(c,p) = X[c,p]*sx[c] + (Y?Y[c,p]:0) ----------------
// grid (13,13,4); block 256. Output tile: 64 co x 8x8 spatial. Per thread 4co x 4pos.
__launch_bounds__(256, 2)
__global__ void conv3x3_kernel(const float* __restrict__ X, const float* __restrict__ sx,
                               const float* __restrict__ Y, const float* __restrict__ Wt,
                               float* __restrict__ out) {
  __shared__ float wl[64 * 196];  // [co][ci(16)*12+k], co stride 196 (bank-spread, 16B aligned)
  __shared__ float il[16 * 120];  // [ci][10 rows][stride 12]
  const int t = threadIdx.x;
  const int ox0 = blockIdx.x * 8, oy0 = blockIdx.y * 8;
  const int cog = blockIdx.z;
  const int p0 = t & 15, c0 = t >> 4;
  const int lx = p0 & 7, ly0 = p0 >> 3;

  float acc[4][4];
#pragma unroll
  for (int i = 0; i < 4; i++)
#pragma unroll
    for (int j = 0; j < 4; j++) acc[i][j] = 0.f;

  for (int cb = 0; cb < NC; cb += 16) {
    __syncthreads();
    // weights: 64co x 16ci x 9
    for (int idx = t; idx < 64 * 16 * 9; idx += 256) {
      const int co = idx / 144;
      const int r = idx - co * 144;
      const int ci = r / 9;
      const int k = r - ci * 9;
      wl[co * 196 + ci * 12 + k] = Wt[(cog * 64 + co) * 2304 + (cb + ci) * 9 + k];
    }
    // input: 16ci x 10x10 (with zero halo)
    for (int idx = t; idx < 1600; idx += 256) {
      const int ci = idx / 100;
      const int r = idx - ci * 100;
      const int iy = r / 10, ix = r - (r / 10) * 10;
      const int gy = oy0 - 1 + iy, gx = ox0 - 1 + ix;
      float v = 0.f;
      if (gy >= 0 && gy < 100 && gx >= 0 && gx < 100) {
        const int gi = (cb + ci) * HW + gy * 100 + gx;
        v = X[gi] * sx[cb + ci];
        if (Y) v += Y[gi];
      }
      il[ci * 120 + iy * 12 + ix] = v;
    }
    __syncthreads();
#pragma unroll 4
    for (int ci = 0; ci < 16; ci++) {
      float wr[4][9];
#pragma unroll
      for (int i = 0; i < 4; i++)
#pragma unroll
        for (int k = 0; k < 9; k++) wr[i][k] = wl[(c0 + 16 * i) * 196 + ci * 12 + k];
      float ir[9][3];
#pragma unroll
      for (int r = 0; r < 9; r++)
#pragma unroll
        for (int cc = 0; cc < 3; cc++) ir[r][cc] = il[ci * 120 + (ly0 + r) * 12 + lx + cc];
#pragma unroll
      for (int i = 0; i < 4; i++)
#pragma unroll
        for (int j = 0; j < 4; j++)
#pragma unroll
          for (int ky = 0; ky < 3; ky++)
#pragma unroll
            for (int kx = 0; kx < 3; kx++)
              acc[i][j] += wr[i][ky * 3 + kx] * ir[2 * j + ky][kx];
    }
  }
#pragma unroll
  for (int i = 0; i < 4; i++) {
#pragma unroll
    for (int j = 0; j < 4; j++) {
      const int co = cog * 64 + c0 + 16 * i;
      const int gy = oy0 + ly0 + 2 * j, gx = ox0 + lx;
      if (gy < 100 && gx < 100) out[co * HW + gy * 100 + gx] = acc[i][j];
    }
  }
}

// ---------------- GroupNorm stats: 8 groups of 32 channels ----------------
__global__ void gn_stats(const float* __restrict__ y, float* __restrict__ gmv) {
  __shared__ float sh[4];
  const int g = blockIdx.x;
  const float* base = y + g * 32 * HW;
  float s = 0.f, ss = 0.f;
  for (int i = threadIdx.x; i < 32 * HW; i += 256) {
    const float v = base[i];
    s += v;
    ss += v * v;
  }
  s = block_sum(s, sh);
  ss = block_sum(ss, sh);
  if (threadIdx.x == 0) {
    const float m = s / (float)(32 * HW);
    const float var = ss / (float)(32 * HW) - m * m;
    gmv[g] = m;
    gmv[8 + g] = rsqrtf(var + 1e-5f);
  }
}

// ---------------- GN apply + relu + weighted accumulate ----------------
__global__ void gn_apply(const float* __restrict__ y, const float* __restrict__ gmv,
                         const float* __restrict__ gn_g, const float* __restrict__ gn_b,
                         const float* __restrict__ wgt, float* __restrict__ asum, int first) {
  const int c = blockIdx.x;
  const int g = c >> 5;
  const float m = gmv[g], rs = gmv[8 + g], ga = gn_g[c], be = gn_b[c], wg = wgt[c];
  for (int i = threadIdx.x; i < HW; i += 256) {
    const float v = fmaxf((y[c * HW + i] - m) * rs * ga + be, 0.f) * wg;
    if (first) asum[c * HW + i] = v;
    else asum[c * HW + i] += v;
  }
}

__global__ void invw_kernel(const float* __restrict__ wgt, float* __restrict__ invw) {
  const int c = threadIdx.x;
  invw[c] = 1.f / (wgt[c] + wgt[256 + c] + 1e-6f);
}

// ---------------- final BN (batch stats) + relu ----------------
__global__ void bn_relu(const float* __restrict__ y, const float* __restrict__ bn_g,
                        const float* __restrict__ bn_b, float* __restrict__ out) {
  __shared__ float sh[4];
  const int c = blockIdx.x;
  float s = 0.f;
  for (int i = threadIdx.x; i < HW; i += 256) s += y[c * HW + i];
  const float m = block_sum(s, sh) * (1.f / (float)HW);
  float ss = 0.f;
  for (int i = threadIdx.x; i < HW; i += 256) {
    const float d = y[c * HW + i] - m;
    ss += d * d;
  }
  const float var = block_sum(ss, sh) * (1.f / (float)HW);
  const float rstd = rsqrtf(var + 1e-5f);
  const float ga = bn_g[c], be = bn_b[c];
  for (int i = threadIdx.x; i < HW; i += 256) {
    out[c * HW + i] = fmaxf((y[c * HW + i] - m) * rstd * ga + be, 0.f);
  }
}

// ---------------- launch ----------------
extern "C" void kernel_launch(void* const* d_in, const int* in_sizes, int n_in,
                              void* d_out, int out_size, void* d_ws, size_t ws_size,
                              hipStream_t stream) {
  const float* cur      = (const float*)d_in[0];
  const float* hist0    = (const float*)d_in[1];
  const float* hist1    = (const float*)d_in[2];
  const float* offset_w = (const float*)d_in[3];
  const float* offset_b = (const float*)d_in[4];
  const float* deform_w = (const float*)d_in[5];
  const float* ca_w1    = (const float*)d_in[6];
  const float* ca_w2    = (const float*)d_in[7];
  const float* out_w    = (const float*)d_in[8];
  const float* gn_g     = (const float*)d_in[9];
  const float* gn_b     = (const float*)d_in[10];
  const float* fuse_w   = (const float*)d_in[11];
  const float* bn_g     = (const float*)d_in[12];
  const float* bn_b     = (const float*)d_in[13];

  float* ws       = (float*)d_ws;
  float* w_off    = ws + WS_OFF;
  float* w_align  = ws + WS_ALIGNED;
  float* w_ybuf   = ws + WS_YBUF;
  float* w_asum   = ws + WS_ASUM;
  float* w_pooled = ws + WS_POOLED;
  float* w_attn   = ws + WS_ATTN;
  float* w_wgt    = ws + WS_WGT;
  float* w_invw   = ws + WS_INVW;
  float* w_gmv    = ws + WS_GMV;

  const float* hists[2] = {hist0, hist1};
  for (int h = 0; h < 2; h++) {
    const float* hist = hists[h];
    offset_gemm<<<40, 256, 0, stream>>>(cur, hist, offset_w, offset_b, w_off);
    deform_kernel<<<dim3(157, 8), 256, 0, stream>>>(hist, w_off, deform_w, w_align);
    reduce_pw<<<256, 256, 0, stream>>>(cur, w_align, hist, w_pooled, w_wgt + h * 256);
    attn_kernel<<<1, 256, 0, stream>>>(w_pooled, ca_w1, ca_w2, w_attn);
    conv3x3_kernel<<<dim3(13, 13, 4), 256, 0, stream>>>(w_align, w_attn, cur, out_w, w_ybuf);
    gn_stats<<<8, 256, 0, stream>>>(w_ybuf, w_gmv);
    gn_apply<<<256, 256, 0, stream>>>(w_ybuf, w_gmv, gn_g, gn_b, w_wgt + h * 256, w_asum,
                                      h == 0 ? 1 : 0);
  }
  invw_kernel<<<1, 256, 0, stream>>>(w_wgt, w_invw);
  conv3x3_kernel<<<dim3(13, 13, 4), 256, 0, stream>>>(w_asum, w_invw, nullptr, fuse_w, w_ybuf);
  bn_relu<<<256, 256, 0, stream>>>(w_ybuf, bn_g, bn_b, (float*)d_out);
}

// Round 6
// 1837.068 us; speedup vs baseline: 1.6193x; 1.6193x over previous
//
#include <hip/hip_runtime.h>
#include <hip/hip_bf16.h>

#define HW 10000
#define NC 256

typedef _Float16 h8 __attribute__((ext_vector_type(8)));
typedef float f32x4 __attribute__((ext_vector_type(4)));

#define RS 40  // f16 elems per LDS patch row: 32 data + 8 pad; 80B rows, 16B-aligned chunks

// swizzled element offset of 16B chunk `chunk` (0..3) in row `pos`
__device__ __forceinline__ int swz(int pos, int chunk) {
  return pos * RS + ((chunk ^ (pos & 3)) << 3);
}

// ---------------- workspace layout (float offsets) ----------------
// Total usage: 8,009,104 floats = 32,036,416 B — UNDER the R1-proven 32,725,184 B.
// Overlays: off[500000] lives in ybuf[0:500000] (off: gemm->deform; ybuf: conv->gn_apply
// — lifetimes disjoint). Conv weight frags built per 128-co half into WS_WMF (294912),
// wprep_half runs immediately before each half-conv.
#define WS_WMF     0          // 294912
#define WS_ALIGNED 294912     // 2560000
#define WS_YBUF    2854912    // 2560000 (off overlay at [2854912, 3354912))
#define WS_ASUM    5414912    // 2560000
#define WS_WOF     7974912    // 32768
#define WS_POOLED  8007680    // 256
#define WS_ATTN    8007936    // 256
#define WS_WGT     8008192    // 512
#define WS_INVW    8008704    // 256
#define WS_GMV     8008960    // 16
#define WS_GNP     8008976    // 128

// ---------------- block-wide sum (256 threads) ----------------
__device__ __forceinline__ float block_sum(float v, volatile float* sh) {
#pragma unroll
  for (int o = 32; o > 0; o >>= 1) v += __shfl_down(v, o);
  __syncthreads();
  if ((threadIdx.x & 63) == 0) sh[threadIdx.x >> 6] = v;
  __syncthreads();
  return sh[0] + sh[1] + sh[2] + sh[3];
}

// ---------------- weight pre-transform, ONE 128-co half ----------------
// frag id = (((cogl*8 + c)*9 + tap)*2 + split)*64 + lane, cogl in [0,8).
// A-frag (16x16x32): lane: row(co)=lane&15, k(ci)=(lane>>4)*8+j.
// split 0 = f16(w); split 1 = f16((w - hi)*2048).
__global__ void wprep_half(const float* __restrict__ W, int half, h8* __restrict__ Wmf) {
  const int id = blockIdx.x * 256 + threadIdx.x;  // 73728
  const int lane = id & 63;
  int rest = id >> 6;
  const int s = rest & 1; rest >>= 1;
  const int tap = rest % 9; rest /= 9;
  const int c = rest & 7;
  const int cogl = rest >> 3;  // 0..7
  const int co = (half * 8 + cogl) * 16 + (lane & 15);
  const int ci0 = c * 32 + (lane >> 4) * 8;
  h8 frag;
#pragma unroll
  for (int j = 0; j < 8; j++) {
    const float w = W[(co * 256 + ci0 + j) * 9 + tap];
    const _Float16 hi = (_Float16)w;
    frag[j] = (s == 0) ? hi : (_Float16)((w - (float)hi) * 2048.f);
  }
  Wmf[id] = frag;
}

// ---------------- weight pre-transform for offset 1x1 (50->pad 64 co, K=512) ----------------
// frag id = ((c*2 + split)*4 + g)*64 + lane
__global__ void wprep2(const float* __restrict__ W, h8* __restrict__ Wof) {
  const int id = blockIdx.x * 256 + threadIdx.x;  // 8192
  const int lane = id & 63;
  int rest = id >> 6;
  const int g = rest & 3; rest >>= 2;
  const int s = rest & 1;
  const int c = rest >> 1;  // 0..15
  const int co = g * 16 + (lane & 15);
  const int ci0 = c * 32 + (lane >> 4) * 8;
  h8 frag;
#pragma unroll
  for (int j = 0; j < 8; j++) {
    const float w = (co < 50) ? W[co * 512 + ci0 + j] : 0.f;
    const _Float16 hi = (_Float16)w;
    frag[j] = (s == 0) ? hi : (_Float16)((w - (float)hi) * 2048.f);
  }
  Wof[id] = frag;
}

// ---------------- offset 1x1 conv via MFMA: out[50,HW] ----------------
// grid 157 blocks, 256 thr. Block: 64 co(50 valid) x 64 pos.
__global__ void gemm1x1_mfma(const float* __restrict__ cur, const float* __restrict__ hist,
                             const h8* __restrict__ Wof, const float* __restrict__ bias,
                             float* __restrict__ out) {
  __shared__ alignas(16) _Float16 Phi[64 * RS];
  __shared__ alignas(16) _Float16 Plo[64 * RS];
  const int t = threadIdx.x, lane = t & 63, wave = t >> 6;
  const int p0 = blockIdx.x * 64;
  const int nl = lane & 15, ksub = lane >> 4;
  f32x4 accM[4], accC[4], accL[4];
#pragma unroll
  for (int g = 0; g < 4; g++) { accM[g] = (f32x4)0.f; accC[g] = (f32x4)0.f; accL[g] = (f32x4)0.f; }
  const int bbase = swz(16 * wave + nl, ksub);

  for (int c = 0; c < 16; c++) {
    __syncthreads();
    // stage 32 ci x 64 pos
    for (int idx = t; idx < 1024; idx += 256) {
      const int cp = idx >> 6;          // ci pair 0..15
      const int pos = idx & 63;
      const int ci = c * 32 + cp * 2;
      const int p = p0 + pos;
      float v0 = 0.f, v1 = 0.f;
      if (p < HW) {
        v0 = (ci < NC) ? cur[ci * HW + p] : hist[(ci - NC) * HW + p];
        v1 = (ci + 1 < NC) ? cur[(ci + 1) * HW + p] : hist[(ci + 1 - NC) * HW + p];
      }
      const _Float16 h0 = (_Float16)v0, h1 = (_Float16)v1;
      const _Float16 l0 = (_Float16)((v0 - (float)h0) * 2048.f);
      const _Float16 l1 = (_Float16)((v1 - (float)h1) * 2048.f);
      const unsigned uh = (unsigned)__builtin_bit_cast(unsigned short, h0) |
                          ((unsigned)__builtin_bit_cast(unsigned short, h1) << 16);
      const unsigned ul = (unsigned)__builtin_bit_cast(unsigned short, l0) |
                          ((unsigned)__builtin_bit_cast(unsigned short, l1) << 16);
      const int ea = swz(pos, cp >> 2) + ((cp & 3) << 1);
      *(unsigned*)&Phi[ea] = uh;
      *(unsigned*)&Plo[ea] = ul;
    }
    __syncthreads();
    const h8 Bh = *(const h8*)&Phi[bbase];
    const h8 Bl = *(const h8*)&Plo[bbase];
#pragma unroll
    for (int g = 0; g < 4; g++) {
      const h8 Ah = Wof[((c * 2 + 0) * 4 + g) * 64 + lane];
      const h8 Al = Wof[((c * 2 + 1) * 4 + g) * 64 + lane];
      accM[g] = __builtin_amdgcn_mfma_f32_16x16x32_f16(Ah, Bh, accM[g], 0, 0, 0);
      accC[g] = __builtin_amdgcn_mfma_f32_16x16x32_f16(Ah, Bl, accC[g], 0, 0, 0);
      accC[g] = __builtin_amdgcn_mfma_f32_16x16x32_f16(Al, Bh, accC[g], 0, 0, 0);
      accL[g] = __builtin_amdgcn_mfma_f32_16x16x32_f16(Al, Bl, accL[g], 0, 0, 0);
    }
  }
#pragma unroll
  for (int g = 0; g < 4; g++) {
#pragma unroll
    for (int j = 0; j < 4; j++) {
      const int co = g * 16 + ksub * 4 + j;
      const int p = p0 + 16 * wave + nl;
      if (co < 50 && p < HW)
        out[co * HW + p] = accM[g][j] + accC[g][j] * (1.f / 2048.f) +
                           accL[g][j] * (1.f / 4194304.f) + bias[co];
    }
  }
}

// ---------------- deformable depthwise conv ----------------
__global__ void deform_kernel(const float* __restrict__ hist, const float* __restrict__ off,
                              const float* __restrict__ dw, float* __restrict__ aligned) {
  const int lane = threadIdx.x & 63;
  const int sub = threadIdx.x >> 6;
  const int p = blockIdx.x * 64 + lane;
  if (p >= HW) return;
  const int y = p / 100;
  const int x = p - y * 100;
  const int cbase = blockIdx.y * 32 + sub * 8;
  float acc[8];
#pragma unroll
  for (int k = 0; k < 8; k++) acc[k] = 0.f;

  for (int t = 0; t < 25; t++) {
    const float dy = off[(2 * t) * HW + p];
    const float dx = off[(2 * t + 1) * HW + p];
    const float ys = (float)(y + t / 5 - 2) + dy;
    const float xs = (float)(x + t % 5 - 2) + dx;
    const float y0f = floorf(ys), x0f = floorf(xs);
    const int y0 = (int)y0f, x0 = (int)x0f;
    const float wy = ys - y0f, wx = xs - x0f;
    const bool vy0 = (y0 >= 0) && (y0 <= 99);
    const bool vy1 = (y0 + 1 >= 0) && (y0 + 1 <= 99);
    const bool vx0 = (x0 >= 0) && (x0 <= 99);
    const bool vx1 = (x0 + 1 >= 0) && (x0 + 1 <= 99);
    const float w00 = (vy0 && vx0) ? (1.f - wy) * (1.f - wx) : 0.f;
    const float w01 = (vy0 && vx1) ? (1.f - wy) * wx : 0.f;
    const float w10 = (vy1 && vx0) ? wy * (1.f - wx) : 0.f;
    const float w11 = (vy1 && vx1) ? wy * wx : 0.f;
    const int yc0 = min(max(y0, 0), 99), yc1 = min(max(y0 + 1, 0), 99);
    const int xc0 = min(max(x0, 0), 99), xc1 = min(max(x0 + 1, 0), 99);
    const int i00 = yc0 * 100 + xc0, i01 = yc0 * 100 + xc1;
    const int i10 = yc1 * 100 + xc0, i11 = yc1 * 100 + xc1;
#pragma unroll
    for (int k = 0; k < 8; k++) {
      const float* hp = hist + (cbase + k) * HW;
      const float s = w00 * hp[i00] + w01 * hp[i01] + w10 * hp[i10] + w11 * hp[i11];
      acc[k] += dw[(cbase + k) * 25 + t] * s;
    }
  }
#pragma unroll
  for (int k = 0; k < 8; k++) aligned[(cbase + k) * HW + p] = acc[k];
}

// ---------------- per-channel reductions ----------------
__global__ void reduce_pw(const float* __restrict__ cur, const float* __restrict__ aligned,
                          const float* __restrict__ hist, float* __restrict__ pooled,
                          float* __restrict__ wgt) {
  __shared__ float sh[4];
  const int c = blockIdx.x;
  float s1 = 0.f, s2 = 0.f;
  for (int i = threadIdx.x; i < HW; i += 256) {
    const float cv = cur[c * HW + i];
    s1 += cv - aligned[c * HW + i];
    s2 += fabsf(cv - hist[c * HW + i]);
  }
  s1 = block_sum(s1, sh);
  s2 = block_sum(s2, sh);
  if (threadIdx.x == 0) {
    pooled[c] = s1 * (1.f / (float)HW);
    wgt[c] = 1.f / (1.f + expf(s2 * (1.f / (float)HW)));
  }
}

// ---------------- channel attention MLP ----------------
__global__ void attn_kernel(const float* __restrict__ pooled, const float* __restrict__ w1,
                            const float* __restrict__ w2, float* __restrict__ attn) {
  __shared__ float pl[256], hid[32];
  const int t = threadIdx.x;
  pl[t] = pooled[t];
  __syncthreads();
  if (t < 32) {
    float s = 0.f;
    for (int c = 0; c < 256; c++) s += w1[t * 256 + c] * pl[c];
    hid[t] = fmaxf(s, 0.f);
  }
  __syncthreads();
  float s = 0.f;
#pragma unroll
  for (int m = 0; m < 32; m++) s += w2[t * 32 + m] * hid[m];
  attn[t] = 1.f / (1.f + expf(-s));
}

// ---------------- 3x3 conv, ONE 128-co half, via MFMA. in = X*sx + (Y?Y:0) ----------------
// grid (13,13); block 256 (4 waves). Block: 128 co x 8x8 pos tile.
__global__ void conv3x3_mfma(const float* __restrict__ X, const float* __restrict__ sx,
                             const float* __restrict__ Y, const h8* __restrict__ Wmf,
                             int half, float* __restrict__ out) {
  __shared__ alignas(16) _Float16 Phi[100 * RS];
  __shared__ alignas(16) _Float16 Plo[100 * RS];
  const int t = threadIdx.x, lane = t & 63, wave = t >> 6;
  const int ox0 = blockIdx.x * 8, oy0 = blockIdx.y * 8;
  const int wc = wave & 1, wn = wave >> 1;
  const int px0 = lane & 7, pyr = (lane >> 3) & 1, ksub = lane >> 4;

  f32x4 accM[4][2], accC[4][2], accL[4][2];
#pragma unroll
  for (int g = 0; g < 4; g++)
#pragma unroll
    for (int n = 0; n < 2; n++) {
      accM[g][n] = (f32x4)0.f; accC[g][n] = (f32x4)0.f; accL[g][n] = (f32x4)0.f;
    }

  int pbase[2];
#pragma unroll
  for (int n = 0; n < 2; n++)
    pbase[n] = (2 * (2 * wn + n) + pyr) * 10 + px0;

  for (int c = 0; c < 8; c++) {
    __syncthreads();
    // stage 32ci x 10x10 halo patch (fused input, f16 hi/lo, lo scaled 2^11)
    for (int idx = t; idx < 1600; idx += 256) {
      const int cp = idx / 100;            // ci pair 0..15
      const int pos = idx - cp * 100;      // 0..99
      const int py = pos / 10, px = pos - py * 10;
      const int gy = oy0 - 1 + py, gx = ox0 - 1 + px;
      const int ci = c * 32 + cp * 2;
      float v0 = 0.f, v1 = 0.f;
      if (gy >= 0 && gy < 100 && gx >= 0 && gx < 100) {
        const int gi = gy * 100 + gx;
        v0 = X[ci * HW + gi] * sx[ci];
        v1 = X[(ci + 1) * HW + gi] * sx[ci + 1];
        if (Y) { v0 += Y[ci * HW + gi]; v1 += Y[(ci + 1) * HW + gi]; }
      }
      const _Float16 h0 = (_Float16)v0, h1 = (_Float16)v1;
      const _Float16 l0 = (_Float16)((v0 - (float)h0) * 2048.f);
      const _Float16 l1 = (_Float16)((v1 - (float)h1) * 2048.f);
      const unsigned uh = (unsigned)__builtin_bit_cast(unsigned short, h0) |
                          ((unsigned)__builtin_bit_cast(unsigned short, h1) << 16);
      const unsigned ul = (unsigned)__builtin_bit_cast(unsigned short, l0) |
                          ((unsigned)__builtin_bit_cast(unsigned short, l1) << 16);
      const int ea = swz(pos, cp >> 2) + ((cp & 3) << 1);
      *(unsigned*)&Phi[ea] = uh;
      *(unsigned*)&Plo[ea] = ul;
    }
    __syncthreads();
#pragma unroll
    for (int ky = 0; ky < 3; ky++) {
#pragma unroll
      for (int kx = 0; kx < 3; kx++) {
        const int tap = ky * 3 + kx;
        h8 Bh[2], Bl[2];
#pragma unroll
        for (int n = 0; n < 2; n++) {
          const int ba = swz(pbase[n] + ky * 10 + kx, ksub);
          Bh[n] = *(const h8*)&Phi[ba];
          Bl[n] = *(const h8*)&Plo[ba];
        }
#pragma unroll
        for (int g = 0; g < 4; g++) {
          const int cogl = wc * 4 + g;  // 0..7 within this half
          const h8* wp = Wmf + (size_t)(((cogl * 8 + c) * 9 + tap) * 2) * 64 + lane;
          const h8 Ah = wp[0];
          const h8 Al = wp[64];
#pragma unroll
          for (int n = 0; n < 2; n++) {
            accM[g][n] = __builtin_amdgcn_mfma_f32_16x16x32_f16(Ah, Bh[n], accM[g][n], 0, 0, 0);
            accC[g][n] = __builtin_amdgcn_mfma_f32_16x16x32_f16(Ah, Bl[n], accC[g][n], 0, 0, 0);
            accC[g][n] = __builtin_amdgcn_mfma_f32_16x16x32_f16(Al, Bh[n], accC[g][n], 0, 0, 0);
            accL[g][n] = __builtin_amdgcn_mfma_f32_16x16x32_f16(Al, Bl[n], accL[g][n], 0, 0, 0);
          }
        }
      }
    }
  }
#pragma unroll
  for (int g = 0; g < 4; g++) {
#pragma unroll
    for (int n = 0; n < 2; n++) {
      const int oy = oy0 + 2 * (2 * wn + n) + pyr;
      const int ox = ox0 + px0;
#pragma unroll
      for (int j = 0; j < 4; j++) {
        const int co = (half * 8 + wc * 4 + g) * 16 + ksub * 4 + j;
        if (oy < 100 && ox < 100)
          out[co * HW + oy * 100 + ox] = accM[g][n][j] + accC[g][n][j] * (1.f / 2048.f) +
                                         accL[g][n][j] * (1.f / 4194304.f);
      }
    }
  }
}

// ---------------- GroupNorm stats, two-stage ----------------
__global__ void gn_partial(const float* __restrict__ y, float* __restrict__ part) {
  __shared__ float sh[4];
  const int bx = blockIdx.x;  // 64: 4 channels each
  const float* base = y + (size_t)bx * 4 * HW;
  float s = 0.f, ss = 0.f;
  for (int i = threadIdx.x; i < 4 * HW; i += 256) {
    const float v = base[i];
    s += v; ss += v * v;
  }
  s = block_sum(s, sh);
  ss = block_sum(ss, sh);
  if (threadIdx.x == 0) { part[bx] = s; part[64 + bx] = ss; }
}

__global__ void gn_final(const float* __restrict__ part, float* __restrict__ gmv) {
  const int g = threadIdx.x;
  if (g < 8) {
    float s = 0.f, ss = 0.f;
#pragma unroll
    for (int j = 0; j < 8; j++) { s += part[g * 8 + j]; ss += part[64 + g * 8 + j]; }
    const float m = s * (1.f / 320000.f);
    const float var = ss * (1.f / 320000.f) - m * m;
    gmv[g] = m;
    gmv[8 + g] = rsqrtf(var + 1e-5f);
  }
}

// ---------------- GN apply + relu + weighted accumulate ----------------
__global__ void gn_apply(const float* __restrict__ y, const float* __restrict__ gmv,
                         const float* __restrict__ gn_g, const float* __restrict__ gn_b,
                         const float* __restrict__ wgt, float* __restrict__ asum, int first) {
  const int c = blockIdx.x;
  const int g = c >> 5;
  const float m = gmv[g], rs = gmv[8 + g], ga = gn_g[c], be = gn_b[c], wg = wgt[c];
  for (int i = threadIdx.x; i < HW; i += 256) {
    const float v = fmaxf((y[c * HW + i] - m) * rs * ga + be, 0.f) * wg;
    if (first) asum[c * HW + i] = v;
    else asum[c * HW + i] += v;
  }
}

__global__ void invw_kernel(const float* __restrict__ wgt, float* __restrict__ invw) {
  const int c = threadIdx.x;
  invw[c] = 1.f / (wgt[c] + wgt[256 + c] + 1e-6f);
}

// ---------------- final BN (batch stats) + relu ----------------
__global__ void bn_relu(const float* __restrict__ y, const float* __restrict__ bn_g,
                        const float* __restrict__ bn_b, float* __restrict__ out) {
  __shared__ float sh[4];
  const int c = blockIdx.x;
  float s = 0.f;
  for (int i = threadIdx.x; i < HW; i += 256) s += y[c * HW + i];
  const float m = block_sum(s, sh) * (1.f / (float)HW);
  float ss = 0.f;
  for (int i = threadIdx.x; i < HW; i += 256) {
    const float d = y[c * HW + i] - m;
    ss += d * d;
  }
  const float var = block_sum(ss, sh) * (1.f / (float)HW);
  const float rstd = rsqrtf(var + 1e-5f);
  const float ga = bn_g[c], be = bn_b[c];
  for (int i = threadIdx.x; i < HW; i += 256) {
    out[c * HW + i] = fmaxf((y[c * HW + i] - m) * rstd * ga + be, 0.f);
  }
}

// ---------------- launch ----------------
extern "C" void kernel_launch(void* const* d_in, const int* in_sizes, int n_in,
                              void* d_out, int out_size, void* d_ws, size_t ws_size,
                              hipStream_t stream) {
  const float* cur      = (const float*)d_in[0];
  const float* hist0    = (const float*)d_in[1];
  const float* hist1    = (const float*)d_in[2];
  const float* offset_w = (const float*)d_in[3];
  const float* offset_b = (const float*)d_in[4];
  const float* deform_w = (const float*)d_in[5];
  const float* ca_w1    = (const float*)d_in[6];
  const float* ca_w2    = (const float*)d_in[7];
  const float* out_w    = (const float*)d_in[8];
  const float* gn_g     = (const float*)d_in[9];
  const float* gn_b     = (const float*)d_in[10];
  const float* fuse_w   = (const float*)d_in[11];
  const float* bn_g     = (const float*)d_in[12];
  const float* bn_b     = (const float*)d_in[13];

  float* ws       = (float*)d_ws;
  float* w_align  = ws + WS_ALIGNED;
  float* w_ybuf   = ws + WS_YBUF;
  float* w_off    = w_ybuf;           // overlay: off dies before conv writes ybuf
  float* w_asum   = ws + WS_ASUM;
  float* w_pooled = ws + WS_POOLED;
  float* w_attn   = ws + WS_ATTN;
  float* w_wgt    = ws + WS_WGT;
  float* w_invw   = ws + WS_INVW;
  float* w_gmv    = ws + WS_GMV;
  float* w_gnp    = ws + WS_GNP;
  h8* wmf = (h8*)(ws + WS_WMF);
  h8* wof = (h8*)(ws + WS_WOF);

  wprep2<<<32, 256, 0, stream>>>(offset_w, wof);

  const float* hists[2] = {hist0, hist1};
  for (int h = 0; h < 2; h++) {
    const float* hist = hists[h];
    gemm1x1_mfma<<<157, 256, 0, stream>>>(cur, hist, wof, offset_b, w_off);
    deform_kernel<<<dim3(157, 8), 256, 0, stream>>>(hist, w_off, deform_w, w_align);
    reduce_pw<<<256, 256, 0, stream>>>(cur, w_align, hist, w_pooled, w_wgt + h * 256);
    attn_kernel<<<1, 256, 0, stream>>>(w_pooled, ca_w1, ca_w2, w_attn);
    for (int half = 0; half < 2; half++) {
      wprep_half<<<288, 256, 0, stream>>>(out_w, half, wmf);
      conv3x3_mfma<<<dim3(13, 13), 256, 0, stream>>>(w_align, w_attn, cur, wmf, half, w_ybuf);
    }
    gn_partial<<<64, 256, 0, stream>>>(w_ybuf, w_gnp);
    gn_final<<<1, 64, 0, stream>>>(w_gnp, w_gmv);
    gn_apply<<<256, 256, 0, stream>>>(w_ybuf, w_gmv, gn_g, gn_b, w_wgt + h * 256, w_asum,
                                      h == 0 ? 1 : 0);
  }
  invw_kernel<<<1, 256, 0, stream>>>(w_wgt, w_invw);
  for (int half = 0; half < 2; half++) {
    wprep_half<<<288, 256, 0, stream>>>(fuse_w, half, wmf);
    conv3x3_mfma<<<dim3(13, 13), 256, 0, stream>>>(w_asum, w_invw, nullptr, wmf, half, w_ybuf);
  }
  bn_relu<<<256, 256, 0, stream>>>(w_ybuf, bn_g, bn_b, (float*)d_out);
}

// Round 7
// 1823.110 us; speedup vs baseline: 1.6316x; 1.0077x over previous
//
#include <hip/hip_runtime.h>
#include <hip/hip_bf16.h>

#define HW 10000
#define NC 256

typedef _Float16 h8 __attribute__((ext_vector_type(8)));
typedef float f32x4 __attribute__((ext_vector_type(4)));

#define RS 40  // f16 elems per LDS patch row: 32 data + 8 pad; 80B rows, 16B-aligned chunks

// swizzled element offset of 16B chunk `chunk` (0..3) in row `pos`
__device__ __forceinline__ int swz(int pos, int chunk) {
  return pos * RS + ((chunk ^ (pos & 3)) << 3);
}

// ---------------- workspace layout (float offsets) ----------------
// IDENTICAL to R6 (proven safe): total 8,009,104 floats = 32,036,416 B.
#define WS_WMF     0          // 294912
#define WS_ALIGNED 294912     // 2560000
#define WS_YBUF    2854912    // 2560000 (off overlay at [2854912, 3354912))
#define WS_ASUM    5414912    // 2560000
#define WS_WOF     7974912    // 32768
#define WS_POOLED  8007680    // 256
#define WS_ATTN    8007936    // 256
#define WS_WGT     8008192    // 512
#define WS_INVW    8008704    // 256
#define WS_GMV     8008960    // 16
#define WS_GNP     8008976    // 128

// ---------------- block-wide sum (256 threads) ----------------
__device__ __forceinline__ float block_sum(float v, volatile float* sh) {
#pragma unroll
  for (int o = 32; o > 0; o >>= 1) v += __shfl_down(v, o);
  __syncthreads();
  if ((threadIdx.x & 63) == 0) sh[threadIdx.x >> 6] = v;
  __syncthreads();
  return sh[0] + sh[1] + sh[2] + sh[3];
}

// ---------------- weight pre-transform, ONE 128-co half ----------------
// Output layout: [c(8)][z(2)][cogl(4)][tap(9)][split(2)][lane(64)] h8 frags.
// The (c,z) slice (4608 frags = 72KB) is the per-chunk LDS weight block.
// A-frag (16x16x32): lane: row(co)=lane&15, k(ci)=(lane>>4)*8+j.
// split 0 = f16(w); split 1 = f16((w - hi)*2048).
__global__ void wprep_half(const float* __restrict__ W, int half, h8* __restrict__ Wmf) {
  const int id = blockIdx.x * 256 + threadIdx.x;  // 73728
  const int lane = id & 63;
  int f = id >> 6;                 // 0..1151
  const int s = f & 1; f >>= 1;    // 0..575
  const int tap = f % 9; f /= 9;   // 0..63
  const int cogl = f & 3; f >>= 2; // 0..15
  const int z = f & 1;
  const int c = f >> 1;            // 0..7
  const int co = ((half * 2 + z) * 4 + cogl) * 16 + (lane & 15);
  const int ci0 = c * 32 + (lane >> 4) * 8;
  h8 frag;
#pragma unroll
  for (int j = 0; j < 8; j++) {
    const float w = W[(co * 256 + ci0 + j) * 9 + tap];
    const _Float16 hi = (_Float16)w;
    frag[j] = (s == 0) ? hi : (_Float16)((w - (float)hi) * 2048.f);
  }
  Wmf[(c * 2 + z) * 4608 + ((cogl * 9 + tap) * 2 + s) * 64 + lane] = frag;
}

// ---------------- weight pre-transform for offset 1x1 (50->pad 64 co, K=512) ----------------
__global__ void wprep2(const float* __restrict__ W, h8* __restrict__ Wof) {
  const int id = blockIdx.x * 256 + threadIdx.x;  // 8192
  const int lane = id & 63;
  int rest = id >> 6;
  const int g = rest & 3; rest >>= 2;
  const int s = rest & 1;
  const int c = rest >> 1;  // 0..15
  const int co = g * 16 + (lane & 15);
  const int ci0 = c * 32 + (lane >> 4) * 8;
  h8 frag;
#pragma unroll
  for (int j = 0; j < 8; j++) {
    const float w = (co < 50) ? W[co * 512 + ci0 + j] : 0.f;
    const _Float16 hi = (_Float16)w;
    frag[j] = (s == 0) ? hi : (_Float16)((w - (float)hi) * 2048.f);
  }
  Wof[id] = frag;
}

// ---------------- offset 1x1 conv via MFMA: out[50,HW] (unchanged from R6) ----------------
__global__ void gemm1x1_mfma(const float* __restrict__ cur, const float* __restrict__ hist,
                             const h8* __restrict__ Wof, const float* __restrict__ bias,
                             float* __restrict__ out) {
  __shared__ alignas(16) _Float16 Phi[64 * RS];
  __shared__ alignas(16) _Float16 Plo[64 * RS];
  const int t = threadIdx.x, lane = t & 63, wave = t >> 6;
  const int p0 = blockIdx.x * 64;
  const int nl = lane & 15, ksub = lane >> 4;
  f32x4 accM[4], accC[4], accL[4];
#pragma unroll
  for (int g = 0; g < 4; g++) { accM[g] = (f32x4)0.f; accC[g] = (f32x4)0.f; accL[g] = (f32x4)0.f; }
  const int bbase = swz(16 * wave + nl, ksub);

  for (int c = 0; c < 16; c++) {
    __syncthreads();
    for (int idx = t; idx < 1024; idx += 256) {
      const int cp = idx >> 6;
      const int pos = idx & 63;
      const int ci = c * 32 + cp * 2;
      const int p = p0 + pos;
      float v0 = 0.f, v1 = 0.f;
      if (p < HW) {
        v0 = (ci < NC) ? cur[ci * HW + p] : hist[(ci - NC) * HW + p];
        v1 = (ci + 1 < NC) ? cur[(ci + 1) * HW + p] : hist[(ci + 1 - NC) * HW + p];
      }
      const _Float16 h0 = (_Float16)v0, h1 = (_Float16)v1;
      const _Float16 l0 = (_Float16)((v0 - (float)h0) * 2048.f);
      const _Float16 l1 = (_Float16)((v1 - (float)h1) * 2048.f);
      const unsigned uh = (unsigned)__builtin_bit_cast(unsigned short, h0) |
                          ((unsigned)__builtin_bit_cast(unsigned short, h1) << 16);
      const unsigned ul = (unsigned)__builtin_bit_cast(unsigned short, l0) |
                          ((unsigned)__builtin_bit_cast(unsigned short, l1) << 16);
      const int ea = swz(pos, cp >> 2) + ((cp & 3) << 1);
      *(unsigned*)&Phi[ea] = uh;
      *(unsigned*)&Plo[ea] = ul;
    }
    __syncthreads();
    const h8 Bh = *(const h8*)&Phi[bbase];
    const h8 Bl = *(const h8*)&Plo[bbase];
#pragma unroll
    for (int g = 0; g < 4; g++) {
      const h8 Ah = Wof[((c * 2 + 0) * 4 + g) * 64 + lane];
      const h8 Al = Wof[((c * 2 + 1) * 4 + g) * 64 + lane];
      accM[g] = __builtin_amdgcn_mfma_f32_16x16x32_f16(Ah, Bh, accM[g], 0, 0, 0);
      accC[g] = __builtin_amdgcn_mfma_f32_16x16x32_f16(Ah, Bl, accC[g], 0, 0, 0);
      accC[g] = __builtin_amdgcn_mfma_f32_16x16x32_f16(Al, Bh, accC[g], 0, 0, 0);
      accL[g] = __builtin_amdgcn_mfma_f32_16x16x32_f16(Al, Bl, accL[g], 0, 0, 0);
    }
  }
#pragma unroll
  for (int g = 0; g < 4; g++) {
#pragma unroll
    for (int j = 0; j < 4; j++) {
      const int co = g * 16 + ksub * 4 + j;
      const int p = p0 + 16 * wave + nl;
      if (co < 50 && p < HW)
        out[co * HW + p] = accM[g][j] + accC[g][j] * (1.f / 2048.f) +
                           accL[g][j] * (1.f / 4194304.f) + bias[co];
    }
  }
}

// ---------------- deformable depthwise conv (unchanged) ----------------
__global__ void deform_kernel(const float* __restrict__ hist, const float* __restrict__ off,
                              const float* __restrict__ dw, float* __restrict__ aligned) {
  const int lane = threadIdx.x & 63;
  const int sub = threadIdx.x >> 6;
  const int p = blockIdx.x * 64 + lane;
  if (p >= HW) return;
  const int y = p / 100;
  const int x = p - y * 100;
  const int cbase = blockIdx.y * 32 + sub * 8;
  float acc[8];
#pragma unroll
  for (int k = 0; k < 8; k++) acc[k] = 0.f;

  for (int t = 0; t < 25; t++) {
    const float dy = off[(2 * t) * HW + p];
    const float dx = off[(2 * t + 1) * HW + p];
    const float ys = (float)(y + t / 5 - 2) + dy;
    const float xs = (float)(x + t % 5 - 2) + dx;
    const float y0f = floorf(ys), x0f = floorf(xs);
    const int y0 = (int)y0f, x0 = (int)x0f;
    const float wy = ys - y0f, wx = xs - x0f;
    const bool vy0 = (y0 >= 0) && (y0 <= 99);
    const bool vy1 = (y0 + 1 >= 0) && (y0 + 1 <= 99);
    const bool vx0 = (x0 >= 0) && (x0 <= 99);
    const bool vx1 = (x0 + 1 >= 0) && (x0 + 1 <= 99);
    const float w00 = (vy0 && vx0) ? (1.f - wy) * (1.f - wx) : 0.f;
    const float w01 = (vy0 && vx1) ? (1.f - wy) * wx : 0.f;
    const float w10 = (vy1 && vx0) ? wy * (1.f - wx) : 0.f;
    const float w11 = (vy1 && vx1) ? wy * wx : 0.f;
    const int yc0 = min(max(y0, 0), 99), yc1 = min(max(y0 + 1, 0), 99);
    const int xc0 = min(max(x0, 0), 99), xc1 = min(max(x0 + 1, 0), 99);
    const int i00 = yc0 * 100 + xc0, i01 = yc0 * 100 + xc1;
    const int i10 = yc1 * 100 + xc0, i11 = yc1 * 100 + xc1;
#pragma unroll
    for (int k = 0; k < 8; k++) {
      const float* hp = hist + (cbase + k) * HW;
      const float s = w00 * hp[i00] + w01 * hp[i01] + w10 * hp[i10] + w11 * hp[i11];
      acc[k] += dw[(cbase + k) * 25 + t] * s;
    }
  }
#pragma unroll
  for (int k = 0; k < 8; k++) aligned[(cbase + k) * HW + p] = acc[k];
}

// ---------------- per-channel reductions (unchanged) ----------------
__global__ void reduce_pw(const float* __restrict__ cur, const float* __restrict__ aligned,
                          const float* __restrict__ hist, float* __restrict__ pooled,
                          float* __restrict__ wgt) {
  __shared__ float sh[4];
  const int c = blockIdx.x;
  float s1 = 0.f, s2 = 0.f;
  for (int i = threadIdx.x; i < HW; i += 256) {
    const float cv = cur[c * HW + i];
    s1 += cv - aligned[c * HW + i];
    s2 += fabsf(cv - hist[c * HW + i]);
  }
  s1 = block_sum(s1, sh);
  s2 = block_sum(s2, sh);
  if (threadIdx.x == 0) {
    pooled[c] = s1 * (1.f / (float)HW);
    wgt[c] = 1.f / (1.f + expf(s2 * (1.f / (float)HW)));
  }
}

// ---------------- channel attention MLP (unchanged) ----------------
__global__ void attn_kernel(const float* __restrict__ pooled, const float* __restrict__ w1,
                            const float* __restrict__ w2, float* __restrict__ attn) {
  __shared__ float pl[256], hid[32];
  const int t = threadIdx.x;
  pl[t] = pooled[t];
  __syncthreads();
  if (t < 32) {
    float s = 0.f;
    for (int c = 0; c < 256; c++) s += w1[t * 256 + c] * pl[c];
    hid[t] = fmaxf(s, 0.f);
  }
  __syncthreads();
  float s = 0.f;
#pragma unroll
  for (int m = 0; m < 32; m++) s += w2[t * 32 + m] * hid[m];
  attn[t] = 1.f / (1.f + expf(-s));
}

// ---------------- 3x3 conv v2: 64co x 256pos blocks, weights in LDS ----------------
// grid (7,7,2); block 256 (4 waves). z selects 64-co group within the 128-co half.
// Per wave: 2 cogs x 8 ngroups. Per chunk: patch 18x18x32ci in LDS (52KB) +
// weight slice 4cog x 9tap x 2split (72KB). in = X*sx + (Y?Y:0).
__launch_bounds__(256, 1)
__global__ void conv3x3_v2(const float* __restrict__ X, const float* __restrict__ sx,
                           const float* __restrict__ Y, const h8* __restrict__ Wmf,
                           int half, float* __restrict__ out) {
  __shared__ alignas(16) _Float16 Phi[324 * RS];
  __shared__ alignas(16) _Float16 Plo[324 * RS];
  __shared__ h8 Wl[4608];
  const int t = threadIdx.x, lane = t & 63, wave = t >> 6;
  const int ox0 = blockIdx.x * 16, oy0 = blockIdx.y * 16;
  const int z = blockIdx.z;
  const int nl = lane & 15, ksub = lane >> 4;
  const int cgbase = (wave & 1) * 2;   // this wave's 2 cogs (within 4-cog block)
  const int ngbase = (wave >> 1) * 8;  // this wave's 8 ngroups (tile rows)

  f32x4 aM[2][8], aC[2][8], aL[2][8];
#pragma unroll
  for (int cc = 0; cc < 2; cc++)
#pragma unroll
    for (int nn = 0; nn < 8; nn++) {
      aM[cc][nn] = (f32x4)0.f; aC[cc][nn] = (f32x4)0.f; aL[cc][nn] = (f32x4)0.f;
    }

  for (int c = 0; c < 8; c++) {
    __syncthreads();
    // stage 32ci x 18x18 halo patch (fused input, f16 hi/lo, lo scaled 2^11)
    for (int idx = t; idx < 5184; idx += 256) {
      const int cp = idx / 324;            // ci pair 0..15
      const int pos = idx - cp * 324;      // 0..323
      const int py = pos / 18, px = pos - py * 18;
      const int gy = oy0 - 1 + py, gx = ox0 - 1 + px;
      const int ci = c * 32 + cp * 2;
      float v0 = 0.f, v1 = 0.f;
      if (gy >= 0 && gy < 100 && gx >= 0 && gx < 100) {
        const int gi = gy * 100 + gx;
        v0 = X[ci * HW + gi] * sx[ci];
        v1 = X[(ci + 1) * HW + gi] * sx[ci + 1];
        if (Y) { v0 += Y[ci * HW + gi]; v1 += Y[(ci + 1) * HW + gi]; }
      }
      const _Float16 h0 = (_Float16)v0, h1 = (_Float16)v1;
      const _Float16 l0 = (_Float16)((v0 - (float)h0) * 2048.f);
      const _Float16 l1 = (_Float16)((v1 - (float)h1) * 2048.f);
      const unsigned uh = (unsigned)__builtin_bit_cast(unsigned short, h0) |
                          ((unsigned)__builtin_bit_cast(unsigned short, h1) << 16);
      const unsigned ul = (unsigned)__builtin_bit_cast(unsigned short, l0) |
                          ((unsigned)__builtin_bit_cast(unsigned short, l1) << 16);
      const int ea = swz(pos, cp >> 2) + ((cp & 3) << 1);
      *(unsigned*)&Phi[ea] = uh;
      *(unsigned*)&Plo[ea] = ul;
    }
    // stage this chunk's weight slice: 4608 frags, coalesced 16B copies
    {
      const h8* __restrict__ wg = Wmf + (c * 2 + z) * 4608;
      for (int i = t; i < 4608; i += 256) Wl[i] = wg[i];
    }
    __syncthreads();
#pragma unroll
    for (int ky = 0; ky < 3; ky++) {
#pragma unroll
      for (int kx = 0; kx < 3; kx++) {
        const int tap = ky * 3 + kx;
        h8 Ah[2], Al[2];
#pragma unroll
        for (int cc = 0; cc < 2; cc++) {
          const int cogl = cgbase + cc;
          Ah[cc] = Wl[((cogl * 9 + tap) * 2 + 0) * 64 + lane];
          Al[cc] = Wl[((cogl * 9 + tap) * 2 + 1) * 64 + lane];
        }
#pragma unroll
        for (int nn = 0; nn < 8; nn++) {
          const int row = (ngbase + nn + ky) * 18 + nl + kx;
          const int ba = swz(row, ksub);
          const h8 Bh = *(const h8*)&Phi[ba];
          const h8 Bl = *(const h8*)&Plo[ba];
#pragma unroll
          for (int cc = 0; cc < 2; cc++) {
            aM[cc][nn] = __builtin_amdgcn_mfma_f32_16x16x32_f16(Ah[cc], Bh, aM[cc][nn], 0, 0, 0);
            aC[cc][nn] = __builtin_amdgcn_mfma_f32_16x16x32_f16(Ah[cc], Bl, aC[cc][nn], 0, 0, 0);
            aC[cc][nn] = __builtin_amdgcn_mfma_f32_16x16x32_f16(Al[cc], Bh, aC[cc][nn], 0, 0, 0);
            aL[cc][nn] = __builtin_amdgcn_mfma_f32_16x16x32_f16(Al[cc], Bl, aL[cc][nn], 0, 0, 0);
          }
        }
      }
    }
  }
  const int ox = ox0 + nl;
#pragma unroll
  for (int cc = 0; cc < 2; cc++) {
    const int co0 = ((half * 2 + z) * 4 + cgbase + cc) * 16 + ksub * 4;
#pragma unroll
    for (int nn = 0; nn < 8; nn++) {
      const int oy = oy0 + ngbase + nn;
      if (oy < 100 && ox < 100) {
#pragma unroll
        for (int j = 0; j < 4; j++) {
          out[(co0 + j) * HW + oy * 100 + ox] =
              aM[cc][nn][j] + aC[cc][nn][j] * (1.f / 2048.f) +
              aL[cc][nn][j] * (1.f / 4194304.f);
        }
      }
    }
  }
}

// ---------------- GroupNorm stats, two-stage (unchanged) ----------------
__global__ void gn_partial(const float* __restrict__ y, float* __restrict__ part) {
  __shared__ float sh[4];
  const int bx = blockIdx.x;  // 64: 4 channels each
  const float* base = y + (size_t)bx * 4 * HW;
  float s = 0.f, ss = 0.f;
  for (int i = threadIdx.x; i < 4 * HW; i += 256) {
    const float v = base[i];
    s += v; ss += v * v;
  }
  s = block_sum(s, sh);
  ss = block_sum(ss, sh);
  if (threadIdx.x == 0) { part[bx] = s; part[64 + bx] = ss; }
}

__global__ void gn_final(const float* __restrict__ part, float* __restrict__ gmv) {
  const int g = threadIdx.x;
  if (g < 8) {
    float s = 0.f, ss = 0.f;
#pragma unroll
    for (int j = 0; j < 8; j++) { s += part[g * 8 + j]; ss += part[64 + g * 8 + j]; }
    const float m = s * (1.f / 320000.f);
    const float var = ss * (1.f / 320000.f) - m * m;
    gmv[g] = m;
    gmv[8 + g] = rsqrtf(var + 1e-5f);
  }
}

// ---------------- GN apply + relu + weighted accumulate (unchanged) ----------------
__global__ void gn_apply(const float* __restrict__ y, const float* __restrict__ gmv,
                         const float* __restrict__ gn_g, const float* __restrict__ gn_b,
                         const float* __restrict__ wgt, float* __restrict__ asum, int first) {
  const int c = blockIdx.x;
  const int g = c >> 5;
  const float m = gmv[g], rs = gmv[8 + g], ga = gn_g[c], be = gn_b[c], wg = wgt[c];
  for (int i = threadIdx.x; i < HW; i += 256) {
    const float v = fmaxf((y[c * HW + i] - m) * rs * ga + be, 0.f) * wg;
    if (first) asum[c * HW + i] = v;
    else asum[c * HW + i] += v;
  }
}

__global__ void invw_kernel(const float* __restrict__ wgt, float* __restrict__ invw) {
  const int c = threadIdx.x;
  invw[c] = 1.f / (wgt[c] + wgt[256 + c] + 1e-6f);
}

// ---------------- final BN (batch stats) + relu (unchanged) ----------------
__global__ void bn_relu(const float* __restrict__ y, const float* __restrict__ bn_g,
                        const float* __restrict__ bn_b, float* __restrict__ out) {
  __shared__ float sh[4];
  const int c = blockIdx.x;
  float s = 0.f;
  for (int i = threadIdx.x; i < HW; i += 256) s += y[c * HW + i];
  const float m = block_sum(s, sh) * (1.f / (float)HW);
  float ss = 0.f;
  for (int i = threadIdx.x; i < HW; i += 256) {
    const float d = y[c * HW + i] - m;
    ss += d * d;
  }
  const float var = block_sum(ss, sh) * (1.f / (float)HW);
  const float rstd = rsqrtf(var + 1e-5f);
  const float ga = bn_g[c], be = bn_b[c];
  for (int i = threadIdx.x; i < HW; i += 256) {
    out[c * HW + i] = fmaxf((y[c * HW + i] - m) * rstd * ga + be, 0.f);
  }
}

// ---------------- launch ----------------
extern "C" void kernel_launch(void* const* d_in, const int* in_sizes, int n_in,
                              void* d_out, int out_size, void* d_ws, size_t ws_size,
                              hipStream_t stream) {
  const float* cur      = (const float*)d_in[0];
  const float* hist0    = (const float*)d_in[1];
  const float* hist1    = (const float*)d_in[2];
  const float* offset_w = (const float*)d_in[3];
  const float* offset_b = (const float*)d_in[4];
  const float* deform_w = (const float*)d_in[5];
  const float* ca_w1    = (const float*)d_in[6];
  const float* ca_w2    = (const float*)d_in[7];
  const float* out_w    = (const float*)d_in[8];
  const float* gn_g     = (const float*)d_in[9];
  const float* gn_b     = (const float*)d_in[10];
  const float* fuse_w   = (const float*)d_in[11];
  const float* bn_g     = (const float*)d_in[12];
  const float* bn_b     = (const float*)d_in[13];

  float* ws       = (float*)d_ws;
  float* w_align  = ws + WS_ALIGNED;
  float* w_ybuf   = ws + WS_YBUF;
  float* w_off    = w_ybuf;           // overlay: off dies before conv writes ybuf
  float* w_asum   = ws + WS_ASUM;
  float* w_pooled = ws + WS_POOLED;
  float* w_attn   = ws + WS_ATTN;
  float* w_wgt    = ws + WS_WGT;
  float* w_invw   = ws + WS_INVW;
  float* w_gmv    = ws + WS_GMV;
  float* w_gnp    = ws + WS_GNP;
  h8* wmf = (h8*)(ws + WS_WMF);
  h8* wof = (h8*)(ws + WS_WOF);

  wprep2<<<32, 256, 0, stream>>>(offset_w, wof);

  const float* hists[2] = {hist0, hist1};
  for (int h = 0; h < 2; h++) {
    const float* hist = hists[h];
    gemm1x1_mfma<<<157, 256, 0, stream>>>(cur, hist, wof, offset_b, w_off);
    deform_kernel<<<dim3(157, 8), 256, 0, stream>>>(hist, w_off, deform_w, w_align);
    reduce_pw<<<256, 256, 0, stream>>>(cur, w_align, hist, w_pooled, w_wgt + h * 256);
    attn_kernel<<<1, 256, 0, stream>>>(w_pooled, ca_w1, ca_w2, w_attn);
    for (int half = 0; half < 2; half++) {
      wprep_half<<<288, 256, 0, stream>>>(out_w, half, wmf);
      conv3x3_v2<<<dim3(7, 7, 2), 256, 0, stream>>>(w_align, w_attn, cur, wmf, half, w_ybuf);
    }
    gn_partial<<<64, 256, 0, stream>>>(w_ybuf, w_gnp);
    gn_final<<<1, 64, 0, stream>>>(w_gnp, w_gmv);
    gn_apply<<<256, 256, 0, stream>>>(w_ybuf, w_gmv, gn_g, gn_b, w_wgt + h * 256, w_asum,
                                      h == 0 ? 1 : 0);
  }
  invw_kernel<<<1, 256, 0, stream>>>(w_wgt, w_invw);
  for (int half = 0; half < 2; half++) {
    wprep_half<<<288, 256, 0, stream>>>(fuse_w, half, wmf);
    conv3x3_v2<<<dim3(7, 7, 2), 256, 0, stream>>>(w_asum, w_invw, nullptr, wmf, half, w_ybuf);
  }
  bn_relu<<<256, 256, 0, stream>>>(w_ybuf, bn_g, bn_b, (float*)d_out);
}